// Round 1
// baseline (124.683 us; speedup 1.0000x reference)
//
#include <hip/hip_runtime.h>
#include <math.h>

// Problem constants (fixed by setup_inputs)
#define NP 8192      // pred vertices
#define NG 12000     // gt vertices
#define NFP 16384    // pred faces
#define NFG 24000    // gt faces
#define EPSF 1e-6f

// uniform grid for NN: 16^3 cells over [0,1]^3, ~3 gt / ~2 pred per cell
#define GR 16
#define NC (GR*GR*GR)        // 4096
#define HCELL 0.0625f        // 1/16, exact power of two
#define QL 16                // lanes cooperating per NN query
#define QPB (256 / QL)       // 16 queries per block
#define PRED_QBLOCKS (NP / QPB)               // 512
#define GT_QBLOCKS (NG / QPB)                 // 750
#define FACE_BLOCKS ((NFG + NFP + 255) / 256) // 158
#define QF_BLOCKS (PRED_QBLOCKS + GT_QBLOCKS + FACE_BLOCKS) // 1420
#define FIN_BLOCKS (NP / 256)                 // 32

// ---- workspace layout (bytes) ----
static constexpr size_t OFF_STARTP = 0;        // (NC+1) u32 cell start (pred), [NC]=NP
static constexpr size_t OFF_STARTG = 16640;    // (NC+1) u32 cell start (gt),  [NC]=NG
static constexpr size_t OFF_SORTP  = 33280;    // 8192  float4 (x,y,z,idx-as-float-bits)
static constexpr size_t OFF_SORTG  = 164352;   // 12000 float4
static constexpr size_t OFF_GTN    = 356352;   // NG*3 f32 gt normal accum (raw)
static constexpr size_t OFF_PNN    = 500352;   // NP*3 f32 pred normal accum
static constexpr size_t OFF_NSUM   = 598656;   // NP*3 f32 laplacian neighbor sum
static constexpr size_t OFF_DEG    = 696960;   // NP   f32 laplacian degree
static constexpr size_t OFF_NEAR   = 729728;   // NP   i32 nearest gt (original idx)
static constexpr size_t OFF_ACCUM  = 762496;   // 8 f32 global accumulators
static constexpr size_t OFF_DONE   = 762528;   // 1 u32 done-counter for finish kernel
// zero region covers gtn..done inclusive (nearestIdx zeroing is harmless)
#define N_ZERO 101545   // (OFF_DONE + 4 - OFF_GTN) / 4

__device__ __forceinline__ int cell_of(float x) {
    int c = (int)(x * (float)GR);
    return min(max(c, 0), GR - 1);
}

// One block builds one point set end-to-end: histogram -> shuffle scan (3
// barriers instead of Hillis-Steele's 20) -> write start[] -> scatter points
// into cell-sorted order using the LDS cursor table. Eliminates the separate
// scatter dispatch: the cursor table never leaves LDS.
__device__ __forceinline__ void build_cells(const float* __restrict__ pts, int n,
                                            unsigned* __restrict__ start,
                                            float4* __restrict__ sorted,
                                            unsigned* h, unsigned* wsum) {
    int t = threadIdx.x;                 // 0..1023
    int lane = t & 63, wid = t >> 6;     // 16 waves
    for (int i = t; i < NC; i += 1024) h[i] = 0u;
    __syncthreads();
    for (int i = t; i < n; i += 1024) {
        int c = (cell_of(pts[3*i+2]) * GR + cell_of(pts[3*i+1])) * GR + cell_of(pts[3*i]);
        atomicAdd(&h[c], 1u);
    }
    __syncthreads();
    // each thread owns 4 cells; wave-shuffle inclusive scan of thread sums
    unsigned a0 = h[4*t], a1 = h[4*t+1], a2 = h[4*t+2], a3 = h[4*t+3];
    unsigned tsum = a0 + a1 + a2 + a3;
    unsigned x = tsum;
    #pragma unroll
    for (int off = 1; off < 64; off <<= 1) {
        unsigned y = __shfl_up(x, off, 64);
        if (lane >= off) x += y;
    }
    if (lane == 63) wsum[wid] = x;       // wave totals
    __syncthreads();
    if (t < 16) {                        // scan 16 wave totals inside wave 0
        unsigned w = wsum[t];
        #pragma unroll
        for (int off = 1; off < 16; off <<= 1) {
            unsigned y = __shfl_up(w, off, 64);
            if (t >= off) w += y;
        }
        wsum[t] = w;                     // inclusive
    }
    __syncthreads();
    unsigned base = (wid ? wsum[wid-1] : 0u) + (x - tsum);  // exclusive prefix
    unsigned e0 = base, e1 = base + a0, e2 = base + a0 + a1, e3 = base + a0 + a1 + a2;
    start[4*t] = e0; start[4*t+1] = e1; start[4*t+2] = e2; start[4*t+3] = e3;
    // reuse h as the scatter cursor (each thread only ever read its own 4 cells)
    h[4*t] = e0; h[4*t+1] = e1; h[4*t+2] = e2; h[4*t+3] = e3;
    __syncthreads();
    for (int i = t; i < n; i += 1024) {
        float px = pts[3*i], py = pts[3*i+1], pz = pts[3*i+2];
        int c = (cell_of(pz) * GR + cell_of(py)) * GR + cell_of(px);
        unsigned pos = atomicAdd(&h[c], 1u);
        sorted[pos] = make_float4(px, py, pz, __int_as_float(i));
    }
    if (t == 0) start[NC] = (unsigned)n;   // end sentinel: end[c] == start[c+1]
}

// Dispatch 1: block 0 = pred build, block 1 = gt build, blocks >=2 zero accums.
__global__ __launch_bounds__(1024) void build_kernel(const float* __restrict__ pred,
                                                     const float* __restrict__ gt,
                                                     unsigned* __restrict__ startP,
                                                     unsigned* __restrict__ startG,
                                                     float4* __restrict__ sortP,
                                                     float4* __restrict__ sortG,
                                                     float* __restrict__ zero) {
    __shared__ unsigned h[NC];
    __shared__ unsigned wsum[16];
    if (blockIdx.x == 0) {
        build_cells(pred, NP, startP, sortP, h, wsum);
    } else if (blockIdx.x == 1) {
        build_cells(gt, NG, startG, sortG, h, wsum);
    } else {
        int i = (blockIdx.x - 2) * 1024 + threadIdx.x;
        if (i < N_ZERO) zero[i] = 0.0f;
    }
}

__device__ __forceinline__ float wave_sum(float x) {
    #pragma unroll
    for (int o = 32; o > 0; o >>= 1) x += __shfl_down(x, o, 64);
    return x;
}

__device__ __forceinline__ unsigned long long u64min(unsigned long long a,
                                                     unsigned long long b) {
    return a < b ? a : b;
}

// Group-parallel NN via expanding-box search over the cell-sorted array.
// Box radius r: (2r+1)^2 (z,y) rows, each row's 2r+1 x-cells are one CONTIGUOUS
// span [start[c0], start[c1+1]). Rows round-robin over the 16 lanes; packed
// (d2bits<<32)|idx 16-lane min-reduce == exact first-occurrence argmin.
// Terminate when best <= blo(r)^2 (blo = distance to nearest in-domain box
// face; faces at the domain border have nothing beyond) or box covers grid.
// r=1 succeeds for ~99.98% of queries. Rescanning inner cells on expansion is
// harmless (min idempotent). All loop conditions are group-uniform.
__device__ __forceinline__ unsigned long long group_nn(int lane,
                                                       float px, float py, float pz,
                                                       const float4* __restrict__ S,
                                                       const unsigned* __restrict__ cstart) {
    int cx = cell_of(px), cy = cell_of(py), cz = cell_of(pz);
    unsigned long long best = 0xFFFFFFFFFFFFFFFFULL;
    for (int r = 1; ; ++r) {
        int w = 2 * r + 1;
        int nrows = w * w;
        int x0 = max(cx - r, 0), x1 = min(cx + r, GR - 1);
        unsigned long long lb = 0xFFFFFFFFFFFFFFFFULL;
        for (int k = lane; k < nrows; k += QL) {
            int z = cz + k / w - r, y = cy + k % w - r;
            if (z >= 0 && z < GR && y >= 0 && y < GR) {
                int rowbase = (z * GR + y) * GR;
                unsigned s0 = cstart[rowbase + x0];
                unsigned s1 = cstart[rowbase + x1 + 1];
                for (unsigned t = s0; t < s1; ++t) {
                    float4 q = S[t];
                    float ddx = px - q.x, ddy = py - q.y, ddz = pz - q.z;
                    float d2 = fmaf(ddx, ddx, fmaf(ddy, ddy, ddz*ddz));
                    unsigned long long key =
                        ((unsigned long long)__float_as_uint(d2) << 32) |
                        (unsigned)__float_as_int(q.w);
                    lb = u64min(lb, key);
                }
            }
        }
        best = u64min(best, lb);
        #pragma unroll
        for (int m = 1; m < QL; m <<= 1)
            best = u64min(best, (unsigned long long)__shfl_xor((long long)best, m, 64));
        bool covered = (cx - r <= 0) & (cx + r >= GR - 1) &
                       (cy - r <= 0) & (cy + r >= GR - 1) &
                       (cz - r <= 0) & (cz + r >= GR - 1);
        if (covered) break;
        float blo = 1.0e30f;
        if (cx - r > 0)      blo = fminf(blo, px - (float)(cx - r) * HCELL);
        if (cx + r < GR - 1) blo = fminf(blo, (float)(cx + r + 1) * HCELL - px);
        if (cy - r > 0)      blo = fminf(blo, py - (float)(cy - r) * HCELL);
        if (cy + r < GR - 1) blo = fminf(blo, (float)(cy + r + 1) * HCELL - py);
        if (cz - r > 0)      blo = fminf(blo, pz - (float)(cz - r) * HCELL);
        if (cz + r < GR - 1) blo = fminf(blo, (float)(cz + r + 1) * HCELL - pz);
        float bd2 = __uint_as_float((unsigned)(best >> 32));
        if (bd2 <= blo * blo) break;   // NaN (no point found) -> false -> expand
    }
    return best;
}

// Dispatch 2: NN queries (pred->gt and gt->pred) run CONCURRENTLY with the
// face-normal/Laplacian atomic scatter — queries no longer touch pnn/gtn/
// nsum/deg (epilogue deferred to finish_kernel), so there is no race.
// Pred queries write nearestIdx[orig v]; dmin sums go straight to accum[].
__global__ __launch_bounds__(256) void query_face_kernel(const float* __restrict__ pred,
                                                         const int* __restrict__ pf,
                                                         const float* __restrict__ gt,
                                                         const int* __restrict__ gf,
                                                         const float4* __restrict__ sortP,
                                                         const float4* __restrict__ sortG,
                                                         const unsigned* __restrict__ startP,
                                                         const unsigned* __restrict__ startG,
                                                         float* __restrict__ gtn,
                                                         float* __restrict__ pnn,
                                                         float* __restrict__ nsum,
                                                         float* __restrict__ deg,
                                                         int* __restrict__ nearestIdx,
                                                         float* __restrict__ accum) {
    int b = blockIdx.x;
    if (b < PRED_QBLOCKS + GT_QBLOCKS) {
        __shared__ float bs;
        if (threadIdx.x == 0) bs = 0.0f;
        __syncthreads();
        int lane = threadIdx.x & (QL - 1);
        int group = threadIdx.x >> 4;            // 0..15
        float r0 = 0.0f;
        if (b < PRED_QBLOCKS) {
            int qid = b * QPB + group;           // < 8192 exact
            float4 P = sortP[qid];
            unsigned long long key = group_nn(lane, P.x, P.y, P.z, sortG, startG);
            if (lane == 0) {
                int v = __float_as_int(P.w);     // original pred index
                nearestIdx[v] = (int)(unsigned)(key & 0xffffffffu);
                r0 = __uint_as_float((unsigned)(key >> 32));
            }
        } else {
            int qid = (b - PRED_QBLOCKS) * QPB + group;  // < 12000 exact
            float4 Q = sortG[qid];
            unsigned long long key = group_nn(lane, Q.x, Q.y, Q.z, sortP, startP);
            if (lane == 0) r0 = __uint_as_float((unsigned)(key >> 32));
        }
        r0 = wave_sum(r0);
        if ((threadIdx.x & 63) == 0) atomicAdd(&bs, r0);
        __syncthreads();
        if (threadIdx.x == 0)
            atomicAdd(&accum[(b < PRED_QBLOCKS) ? 0 : 6], bs);
    } else {
        int t = (b - PRED_QBLOCKS - GT_QBLOCKS) * 256 + threadIdx.x;
        if (t < NFG) {
            int i0 = gf[3*t], i1 = gf[3*t+1], i2 = gf[3*t+2];
            float ax = gt[3*i0], ay = gt[3*i0+1], az = gt[3*i0+2];
            float bx = gt[3*i1], by = gt[3*i1+1], bz = gt[3*i1+2];
            float cx = gt[3*i2], cy = gt[3*i2+1], cz = gt[3*i2+2];
            float ux = bx-ax, uy = by-ay, uz = bz-az;
            float wx = cx-ax, wy = cy-ay, wz = cz-az;
            float nx = uy*wz - uz*wy, ny = uz*wx - ux*wz, nz = ux*wy - uy*wx;
            atomicAdd(&gtn[3*i0+0], nx); atomicAdd(&gtn[3*i0+1], ny); atomicAdd(&gtn[3*i0+2], nz);
            atomicAdd(&gtn[3*i1+0], nx); atomicAdd(&gtn[3*i1+1], ny); atomicAdd(&gtn[3*i1+2], nz);
            atomicAdd(&gtn[3*i2+0], nx); atomicAdd(&gtn[3*i2+1], ny); atomicAdd(&gtn[3*i2+2], nz);
        } else if (t < NFG + NFP) {
            int u = t - NFG;
            int i0 = pf[3*u], i1 = pf[3*u+1], i2 = pf[3*u+2];
            float ax = pred[3*i0], ay = pred[3*i0+1], az = pred[3*i0+2];
            float bx = pred[3*i1], by = pred[3*i1+1], bz = pred[3*i1+2];
            float cx = pred[3*i2], cy = pred[3*i2+1], cz = pred[3*i2+2];
            float ux = bx-ax, uy = by-ay, uz = bz-az;
            float wx = cx-ax, wy = cy-ay, wz = cz-az;
            float nx = uy*wz - uz*wy, ny = uz*wx - ux*wz, nz = ux*wy - uy*wx;
            atomicAdd(&pnn[3*i0+0], nx); atomicAdd(&pnn[3*i0+1], ny); atomicAdd(&pnn[3*i0+2], nz);
            atomicAdd(&pnn[3*i1+0], nx); atomicAdd(&pnn[3*i1+1], ny); atomicAdd(&pnn[3*i1+2], nz);
            atomicAdd(&pnn[3*i2+0], nx); atomicAdd(&pnn[3*i2+1], ny); atomicAdd(&pnn[3*i2+2], nz);
            atomicAdd(&nsum[3*i0+0], bx+cx); atomicAdd(&nsum[3*i0+1], by+cy); atomicAdd(&nsum[3*i0+2], bz+cz);
            atomicAdd(&nsum[3*i1+0], cx+ax); atomicAdd(&nsum[3*i1+1], cy+ay); atomicAdd(&nsum[3*i1+2], cz+az);
            atomicAdd(&nsum[3*i2+0], ax+bx); atomicAdd(&nsum[3*i2+1], ay+by); atomicAdd(&nsum[3*i2+2], az+bz);
            atomicAdd(&deg[i0], 2.0f); atomicAdd(&deg[i1], 2.0f); atomicAdd(&deg[i2], 2.0f);
        }
    }
}

// Dispatch 3: fully-parallel per-vertex epilogue (normal consistency,
// laplacian, spatial focal terms) — previously done serially by lane 0 of
// each 16-lane group. Block partials -> global atomic accum; last block
// (done-counter, device-scope) computes the final scalar.
__global__ __launch_bounds__(256) void finish_kernel(const float* __restrict__ pred,
                                                     const float* __restrict__ relpos,
                                                     const int* __restrict__ label,
                                                     const float* __restrict__ pnn,
                                                     const float* __restrict__ gtn,
                                                     const float* __restrict__ nsum,
                                                     const float* __restrict__ deg,
                                                     const int* __restrict__ nearestIdx,
                                                     float* __restrict__ accum,
                                                     unsigned* __restrict__ done,
                                                     float* __restrict__ out) {
    int v = blockIdx.x * 256 + threadIdx.x;     // < 8192 exact
    float px = pred[3*v], py = pred[3*v+1], pz = pred[3*v+2];
    int nearest = nearestIdx[v];

    // normal consistency (normalize both accumulators on the fly)
    float ax = pnn[3*v], ay = pnn[3*v+1], az = pnn[3*v+2];
    float an = fmaxf(sqrtf(ax*ax + ay*ay + az*az), EPSF);
    float gx = gtn[3*nearest], gy = gtn[3*nearest+1], gz = gtn[3*nearest+2];
    float gn = fmaxf(sqrtf(gx*gx + gy*gy + gz*gz), EPSF);
    float nx = ax/an - gx/gn, ny = ay/an - gy/gn, nz = az/an - gz/gn;
    float sse = nx*nx + ny*ny + nz*nz;

    // laplacian
    float d = fmaxf(deg[v], 1.0f);
    float lx = nsum[3*v]/d - px, ly = nsum[3*v+1]/d - py, lz = nsum[3*v+2]/d - pz;
    float lapn = sqrtf(lx*lx + ly*ly + lz*lz);

    // grid-sample target (nearest, align_corners=True, zeros padding)
    int ix = (int)rintf(px * 95.0f), iy = (int)rintf(py * 95.0f), iz = (int)rintf(pz * 95.0f);
    bool inb = (ix >= 0) & (ix < 96) & (iy >= 0) & (iy < 96) & (iz >= 0) & (iz < 96);
    int ixc = min(max(ix, 0), 95), iyc = min(max(iy, 0), 95), izc = min(max(iz, 0), 95);
    bool pos = inb && (label[(izc*96 + iyc)*96 + ixc] == 1);

    float p = fminf(fmaxf(relpos[v], EPSF), 1.0f - EPSF);
    float om = 1.0f - p;
    float pcnt = 0.0f, sx = 0.0f, sy = 0.0f;
    if (pos) { pcnt = 1.0f; sx = om*om*logf(p); }
    else     { sy = p*p*logf(om); }

    float r1 = wave_sum(sse), r2 = wave_sum(lapn), r3 = wave_sum(pcnt);
    float r4 = wave_sum(sx),  r5 = wave_sum(sy);
    __shared__ float bsum[5];
    __shared__ bool isLast;
    if (threadIdx.x < 5) bsum[threadIdx.x] = 0.0f;
    __syncthreads();
    if ((threadIdx.x & 63) == 0) {
        atomicAdd(&bsum[0], r1); atomicAdd(&bsum[1], r2); atomicAdd(&bsum[2], r3);
        atomicAdd(&bsum[3], r4); atomicAdd(&bsum[4], r5);
    }
    __syncthreads();
    if (threadIdx.x == 0) {
        atomicAdd(&accum[1], bsum[0]); atomicAdd(&accum[2], bsum[1]);
        atomicAdd(&accum[3], bsum[2]); atomicAdd(&accum[4], bsum[3]);
        atomicAdd(&accum[5], bsum[4]);
        __threadfence();                         // publish before done-count
        unsigned prev = atomicAdd(done, 1u);
        isLast = (prev == FIN_BLOCKS - 1);
    }
    __syncthreads();
    if (isLast && threadIdx.x == 0) {
        __threadfence();
        float sum_row = __hip_atomic_load(&accum[0], __ATOMIC_RELAXED, __HIP_MEMORY_SCOPE_AGENT);
        float sse_t   = __hip_atomic_load(&accum[1], __ATOMIC_RELAXED, __HIP_MEMORY_SCOPE_AGENT);
        float lap_t   = __hip_atomic_load(&accum[2], __ATOMIC_RELAXED, __HIP_MEMORY_SCOPE_AGENT);
        float pc      = __hip_atomic_load(&accum[3], __ATOMIC_RELAXED, __HIP_MEMORY_SCOPE_AGENT);
        float SX      = __hip_atomic_load(&accum[4], __ATOMIC_RELAXED, __HIP_MEMORY_SCOPE_AGENT);
        float SY      = __hip_atomic_load(&accum[5], __ATOMIC_RELAXED, __HIP_MEMORY_SCOPE_AGENT);
        float sum_col = __hip_atomic_load(&accum[6], __ATOMIC_RELAXED, __HIP_MEMORY_SCOPE_AGENT);
        float tot = (float)NP;
        float alpha = (tot - pc) / (tot + EPSF);
        float spatial = (-alpha * SX - (1.0f - alpha) * SY) / (tot + EPSF);
        float distance = sum_row / (float)NP + sum_col / (float)NG;
        float normal = sse_t / (float)(NP * 3);
        float lapm = lap_t / (float)NP;
        out[0] = spatial + 1.0f * distance + 0.01f * normal + 0.1f * lapm;
    }
}

extern "C" void kernel_launch(void* const* d_in, const int* in_sizes, int n_in,
                              void* d_out, int out_size, void* d_ws, size_t ws_size,
                              hipStream_t stream) {
    const float* pred   = (const float*)d_in[0];   // [8192,3]
    const float* relpos = (const float*)d_in[1];   // [8192]
    const float* gt     = (const float*)d_in[2];   // [12000,3]
    const int*   pfaces = (const int*)d_in[3];     // [16384,3]
    const int*   gfaces = (const int*)d_in[4];     // [24000,3]
    const int*   label  = (const int*)d_in[5];     // [1,1,96,96,96]
    float* out = (float*)d_out;

    char* ws = (char*)d_ws;
    unsigned* startP  = (unsigned*)(ws + OFF_STARTP);
    unsigned* startG  = (unsigned*)(ws + OFF_STARTG);
    float4*   sortP   = (float4*)(ws + OFF_SORTP);
    float4*   sortG   = (float4*)(ws + OFF_SORTG);
    float*    gtn     = (float*)(ws + OFF_GTN);
    float*    pnn     = (float*)(ws + OFF_PNN);
    float*    nsum    = (float*)(ws + OFF_NSUM);
    float*    deg     = (float*)(ws + OFF_DEG);
    int*      nearest = (int*)(ws + OFF_NEAR);
    float*    accum   = (float*)(ws + OFF_ACCUM);
    unsigned* done    = (unsigned*)(ws + OFF_DONE);

    // d1: hist+scan+scatter (blocks 0,1) || zero accumulators (blocks 2..)
    int zero_blocks = (N_ZERO + 1023) / 1024;      // 100
    hipLaunchKernelGGL(build_kernel, dim3(2 + zero_blocks), dim3(1024), 0, stream,
                       pred, gt, startP, startG, sortP, sortG, (float*)(ws + OFF_GTN));
    // d2: grid-NN queries || face-normal/laplacian atomic scatter (concurrent)
    hipLaunchKernelGGL(query_face_kernel, dim3(QF_BLOCKS), dim3(256), 0, stream,
                       pred, pfaces, gt, gfaces, sortP, sortG, startP, startG,
                       gtn, pnn, nsum, deg, nearest, accum);
    // d3: parallel per-vertex epilogue + last-block final combine
    hipLaunchKernelGGL(finish_kernel, dim3(FIN_BLOCKS), dim3(256), 0, stream,
                       pred, relpos, label, pnn, gtn, nsum, deg, nearest,
                       accum, done, out);
}